// Round 7
// baseline (2059.865 us; speedup 1.0000x reference)
//
#include <hip/hip_runtime.h>

// Conv2d 3x3, cin=4, cout=4, pad=1, stride=1 on [4,4096,4096] fp32.
//
// Round-7: occupancy x ILP balance. Thread = 8 px x 1 row x 4 cout
// (acc 32, VGPR ~75 -> 6 waves/SIMD via __launch_bounds__(256,6)).
// Per cin: BATCH all 3 input rows' loads (12 instrs: 2 halo scalars issued
// first + 2 aligned dwordx4, per row), then 288 FMAs (576 cy window).
// 6 waves x 45% duty ~ 2.7x VALU oversubscription -> latency covered.
// Grid 8192 (4096 rows x 2 half-rows), XCD-bijective swizzle: 512-row band
// per XCD keeps the 3-row x 4-cin reuse window (~192 KB) L2-resident.

#define IW 4096
#define IH 4096
constexpr long long HWsz = (long long)IH * IW;

typedef float v4f __attribute__((ext_vector_type(4)));

__global__ __launch_bounds__(256, 6) void conv3x3_kernel(
    const float* __restrict__ xin,   // [4][4096][4096]
    const float* __restrict__ wt,    // [4][4][3][3]
    float* __restrict__ out)         // [4][4096][4096]
{
    // grid 8192; bijective XCD swizzle (8192 % 8 == 0)
    const int bid = blockIdx.x;
    const int swz = (bid & 7) * 1024 + (bid >> 3);
    const int y   = swz >> 1;                        // output row
    const int x0  = (swz & 1) * 2048 + (int)threadIdx.x * 8;

    const bool x_lo = (x0 == 0);
    const bool x_hi = (x0 + 8 == IW);

    float acc[4][8];                                 // [cout][px]
    #pragma unroll
    for (int co = 0; co < 4; ++co)
        #pragma unroll
        for (int p = 0; p < 8; ++p) acc[co][p] = 0.f;

    #pragma unroll
    for (int ci = 0; ci < 4; ++ci) {
        const float* plane = xin + (long long)ci * HWsz;
        float v[3][10];
        // ---- batched loads: all 3 input rows of this cin (12 instrs) ----
        #pragma unroll
        for (int r = 0; r < 3; ++r) {
            const int yy = y + r - 1;
            if (yy >= 0 && yy < IH) {                // wave-uniform branch
                const float* rowp = plane + (long long)yy * IW;
                v[r][0] = x_lo ? 0.f : rowp[x0 - 1]; // gathers issued first
                v[r][9] = x_hi ? 0.f : rowp[x0 + 8];
                const v4f a = *reinterpret_cast<const v4f*>(rowp + x0);
                const v4f b = *reinterpret_cast<const v4f*>(rowp + x0 + 4);
                v[r][1] = a.x; v[r][2] = a.y; v[r][3] = a.z; v[r][4] = a.w;
                v[r][5] = b.x; v[r][6] = b.y; v[r][7] = b.z; v[r][8] = b.w;
            } else {
                #pragma unroll
                for (int t = 0; t < 10; ++t) v[r][t] = 0.f;
            }
        }
        // ---- 288 FMAs on the batch ----
        #pragma unroll
        for (int r = 0; r < 3; ++r) {
            #pragma unroll
            for (int co = 0; co < 4; ++co) {
                #pragma unroll
                for (int kx = 0; kx < 3; ++kx) {
                    const float w = wt[((co * 4 + ci) * 3 + r) * 3 + kx];
                    #pragma unroll
                    for (int p = 0; p < 8; ++p)
                        acc[co][p] = fmaf(w, v[r][p + kx], acc[co][p]);
                }
            }
        }
    }

    const long long obase = (long long)y * IW + x0;
    #pragma unroll
    for (int co = 0; co < 4; ++co) {
        v4f o0, o1;
        o0.x = acc[co][0]; o0.y = acc[co][1]; o0.z = acc[co][2]; o0.w = acc[co][3];
        o1.x = acc[co][4]; o1.y = acc[co][5]; o1.z = acc[co][6]; o1.w = acc[co][7];
        *reinterpret_cast<v4f*>(out + co * HWsz + obase)     = o0;
        *reinterpret_cast<v4f*>(out + co * HWsz + obase + 4) = o1;
    }
}

extern "C" void kernel_launch(void* const* d_in, const int* in_sizes, int n_in,
                              void* d_out, int out_size, void* d_ws, size_t ws_size,
                              hipStream_t stream) {
    const float* xin = (const float*)d_in[0];
    const float* wt  = (const float*)d_in[1];
    float* out       = (float*)d_out;

    dim3 grid(8192), block(256);
    hipLaunchKernelGGL(conv3x3_kernel, grid, block, 0, stream, xin, wt, out);
}

// Round 8
// 122.906 us; speedup vs baseline: 16.7596x; 16.7596x over previous
//
#include <hip/hip_runtime.h>

// Conv2d 3x3, cin=4, cout=4, pad=1, stride=1 on [4,4096,4096] fp32.
//
// Round-8: LDS row staging (guide G3). Block = 1024px x 4 output rows;
// thread = 4px x 4rows x 4cout (64 acc). Per ci: stage 6 input rows
// (x in [X0-1, X0+1025)) into LDS with coalesced dwordx4 (edge lanes fix
// borders), barrier, then per row 2 contiguous ds_read_b128 (conflict-free,
// no strided halo gathers) + 576 FMAs. ci loop kept rolled (#pragma unroll 1)
// for I$-fit. VMEM instrs/thread 88 -> ~40, all coalesced. NT stores keep
// the write stream from evicting the L3-resident input.

#define IW 4096
#define IH 4096
constexpr long long HWsz = (long long)IH * IW;

typedef float v4f __attribute__((ext_vector_type(4)));

#define LROW 1032   // floats per LDS row: 1026 used (+ pad for the b-read tail)

__global__ __launch_bounds__(256) void conv3x3_kernel(
    const float* __restrict__ xin,   // [4][4096][4096]
    const float* __restrict__ wt,    // [4][4][3][3]
    float* __restrict__ out)         // [4][4096][4096]
{
    __shared__ float lds[6][LROW];   // 24768 B

    // grid 4096 = 1024 row-blocks x 4 x-strips; bijective XCD swizzle
    const int bid = blockIdx.x;
    const int swz = (bid & 7) * 512 + (bid >> 3);
    const int rowblk = swz >> 2;                 // 0..1023
    const int xq     = swz & 3;                  // 0..3
    const int y0     = rowblk << 2;              // 4 output rows
    const int X0     = xq << 10;                 // 1024-px x strip
    const int t      = (int)threadIdx.x;

    const int xg = X0 - 1 + 4 * t;               // global x of lds col 4t

    float acc[4][4][4];                          // [orow][cout][px]
    #pragma unroll
    for (int o = 0; o < 4; ++o)
        #pragma unroll
        for (int co = 0; co < 4; ++co)
            #pragma unroll
            for (int p = 0; p < 4; ++p) acc[o][co][p] = 0.f;

    #pragma unroll 1
    for (int ci = 0; ci < 4; ++ci) {
        const float* plane = xin + (long long)ci * HWsz;

        __syncthreads();                         // prev iter's reads done
        // ---- stage 6 input rows into LDS (coalesced dwordx4) ----
        #pragma unroll
        for (int r = 0; r < 6; ++r) {
            const int yy = y0 - 1 + r;
            if (yy >= 0 && yy < IH) {            // wave-uniform
                const float* rowp = plane + (long long)yy * IW;
                v4f m;
                if (xg >= 0) {                   // all but lane0 of xq==0
                    m = *reinterpret_cast<const v4f*>(rowp + xg);
                } else {                         // image left edge: zero pad
                    m.x = 0.f; m.y = rowp[0]; m.z = rowp[1]; m.w = rowp[2];
                }
                *reinterpret_cast<v4f*>(&lds[r][4 * t]) = m;
                if (t < 2) {                     // tail cols j=1024,1025
                    const int xt = X0 + 1023 + t;
                    lds[r][1024 + t] = (xt < IW) ? rowp[xt] : 0.f;
                }
            } else {                             // vertical zero pad
                v4f z = {0.f, 0.f, 0.f, 0.f};
                *reinterpret_cast<v4f*>(&lds[r][4 * t]) = z;
                if (t < 2) lds[r][1024 + t] = 0.f;
            }
        }
        __syncthreads();

        // ---- compute: per input row, 2 contiguous b128 reads + FMAs ----
        #pragma unroll
        for (int dy = 0; dy < 6; ++dy) {
            const v4f a = *reinterpret_cast<const v4f*>(&lds[dy][4 * t]);
            const v4f b = *reinterpret_cast<const v4f*>(&lds[dy][4 * t + 4]);
            float vv[6];
            vv[0] = a.x; vv[1] = a.y; vv[2] = a.z; vv[3] = a.w;
            vv[4] = b.x; vv[5] = b.y;
            #pragma unroll
            for (int rk = 0; rk < 3; ++rk) {
                const int o = dy - rk;           // output row offset
                if (o >= 0 && o < 4) {
                    #pragma unroll
                    for (int co = 0; co < 4; ++co) {
                        #pragma unroll
                        for (int kx = 0; kx < 3; ++kx) {
                            const float w = wt[((co * 4 + ci) * 3 + rk) * 3 + kx];
                            #pragma unroll
                            for (int p = 0; p < 4; ++p)
                                acc[o][co][p] = fmaf(w, vv[p + kx], acc[o][co][p]);
                        }
                    }
                }
            }
        }
    }

    // ---- store: 16 nontemporal dwordx4 ----
    const int x0g = X0 + 4 * t;
    #pragma unroll
    for (int o = 0; o < 4; ++o) {
        const long long obase = (long long)(y0 + o) * IW + x0g;
        #pragma unroll
        for (int co = 0; co < 4; ++co) {
            v4f ov;
            ov.x = acc[o][co][0]; ov.y = acc[o][co][1];
            ov.z = acc[o][co][2]; ov.w = acc[o][co][3];
            __builtin_nontemporal_store(ov,
                reinterpret_cast<v4f*>(out + co * HWsz + obase));
        }
    }
}

extern "C" void kernel_launch(void* const* d_in, const int* in_sizes, int n_in,
                              void* d_out, int out_size, void* d_ws, size_t ws_size,
                              hipStream_t stream) {
    const float* xin = (const float*)d_in[0];
    const float* wt  = (const float*)d_in[1];
    float* out       = (float*)d_out;

    dim3 grid(4096), block(256);
    hipLaunchKernelGGL(conv3x3_kernel, grid, block, 0, stream, xin, wt, out);
}

// Round 9
// 97.870 us; speedup vs baseline: 21.0469x; 1.2558x over previous
//
#include <hip/hip_runtime.h>

// Conv2d 3x3, cin=4, cout=4, pad=1, stride=1 on [4,4096,4096] fp32.
//
// Round-9: 2-phase pipelined LDS staging (T3-lite + global_load_lds).
// Block = 1024px x 4 output rows; thread = 4px x 4rows x 4cout (64 acc).
// Per ci: 6 input rows DMA'd straight to LDS via global_load_lds width=16
// (wave-uniform dest + lane*16 = our exact linear layout), 2 halo columns
// via one width=4 DMA per wave (lanes 0..2 -> 3 slots each, 12 total).
// Double-buffered: stage(ci+1) issued BEFORE compute(ci); raw s_barrier with
// counted s_waitcnt vmcnt(7) (7 DMAs/wave/stage in flight) -- never drain
// to 0 in the loop. Vertical pad rows: DMA source clamped (garbage staged),
// compute skips those dy wave-uniformly. Image-edge x zeros via cndmask on
// the t==0 / t==255 halo values.

#define IW 4096
#define IH 4096
constexpr long long HWsz = (long long)IH * IW;

typedef float v4f __attribute__((ext_vector_type(4)));

#define LROW 1028   // 1024 interior floats + pad (4112 B, 16B multiple)

__device__ __forceinline__ void gload_lds16(const float* g, float* l) {
    __builtin_amdgcn_global_load_lds(
        (const __attribute__((address_space(1))) char*)g,
        (__attribute__((address_space(3))) char*)l, 16, 0, 0);
}
__device__ __forceinline__ void gload_lds4(const float* g, float* l) {
    __builtin_amdgcn_global_load_lds(
        (const __attribute__((address_space(1))) char*)g,
        (__attribute__((address_space(3))) char*)l, 4, 0, 0);
}

// issue 7 DMAs per wave: 6 interior row-chunks (width 16) + 1 halo (width 4)
__device__ __forceinline__ void stage(const float* __restrict__ xin, int ci,
                                      float (*rbuf)[LROW], float* hbuf,
                                      int y0, int X0, int w, int l) {
    const float* plane = xin + (long long)ci * HWsz;
    const int xg = X0 + 256 * w + 4 * l;          // per-lane global x
    #pragma unroll
    for (int r = 0; r < 6; ++r) {
        int yy = y0 - 1 + r;
        int yc = yy < 0 ? 0 : (yy >= IH ? IH - 1 : yy);   // clamp: pad rows
        gload_lds16(plane + (long long)yc * IW + xg, &rbuf[r][256 * w]);
    }
    if (l < 3) {                                   // 4 waves x 3 lanes = 12 slots
        const int s   = 3 * w + l;                 // slot = 2*r + side
        const int r   = s >> 1;
        const int sid = s & 1;
        int yy = y0 - 1 + r;
        int yc = yy < 0 ? 0 : (yy >= IH ? IH - 1 : yy);
        int x  = sid ? (X0 + 1024) : (X0 - 1);
        int xc = x < 0 ? 0 : (x >= IW ? IW - 1 : x);
        gload_lds4(plane + (long long)yc * IW + xc, &hbuf[3 * w]);
    }
}

__device__ __forceinline__ void compute_ci(float acc[4][4][4],
                                           const float (*rbuf)[LROW],
                                           const float* hbuf,
                                           const float* __restrict__ wt, int ci,
                                           int y0, int t, bool xlo, bool xhi) {
    #pragma unroll
    for (int dy = 0; dy < 6; ++dy) {
        const int yy = y0 - 1 + dy;
        if (yy >= 0 && yy < IH) {                  // wave-uniform row skip
            const v4f a = *reinterpret_cast<const v4f*>(&rbuf[dy][4 * t]);
            float L = (t == 0)   ? hbuf[2 * dy]     : rbuf[dy][4 * t - 1];
            float R = (t == 255) ? hbuf[2 * dy + 1] : rbuf[dy][4 * t + 4];
            if (t == 0 && xlo)   L = 0.f;          // image left edge
            if (t == 255 && xhi) R = 0.f;          // image right edge
            float vv[6] = {L, a.x, a.y, a.z, a.w, R};
            #pragma unroll
            for (int rk = 0; rk < 3; ++rk) {
                const int o = dy - rk;             // output row offset
                if (o >= 0 && o < 4) {
                    #pragma unroll
                    for (int co = 0; co < 4; ++co) {
                        #pragma unroll
                        for (int kx = 0; kx < 3; ++kx) {
                            const float w = wt[((co * 4 + ci) * 3 + rk) * 3 + kx];
                            #pragma unroll
                            for (int p = 0; p < 4; ++p)
                                acc[o][co][p] = fmaf(w, vv[p + kx], acc[o][co][p]);
                        }
                    }
                }
            }
        }
    }
}

__global__ __launch_bounds__(256) void conv3x3_kernel(
    const float* __restrict__ xin,   // [4][4096][4096]
    const float* __restrict__ wt,    // [4][4][3][3]
    float* __restrict__ out)         // [4][4096][4096]
{
    __shared__ __align__(16) float rows[2][6][LROW];   // 49344 B
    __shared__ float halo[2][12];

    // grid 4096 = 1024 row-blocks x 4 x-strips; bijective XCD swizzle
    const int bid = blockIdx.x;
    const int swz = (bid & 7) * 512 + (bid >> 3);
    const int rowblk = swz >> 2;
    const int xq     = swz & 3;
    const int y0     = rowblk << 2;               // 4 output rows
    const int X0     = xq << 10;                  // 1024-px strip
    const int t      = (int)threadIdx.x;
    const int w      = t >> 6, l = t & 63;
    const bool xlo   = (X0 == 0);
    const bool xhi   = (X0 + 1024 == IW);

    float acc[4][4][4];
    #pragma unroll
    for (int o = 0; o < 4; ++o)
        #pragma unroll
        for (int co = 0; co < 4; ++co)
            #pragma unroll
            for (int p = 0; p < 4; ++p) acc[o][co][p] = 0.f;

    stage(xin, 0, rows[0], halo[0], y0, X0, w, l);   // prologue

    #pragma unroll 1
    for (int ci = 0; ci < 4; ++ci) {
        const int cur = ci & 1;
        if (ci < 3) {
            stage(xin, ci + 1, rows[cur ^ 1], halo[cur ^ 1], y0, X0, w, l);
            // wait the OLDEST 7 (= ci's loads); ci+1's 7 stay in flight
            asm volatile("s_waitcnt vmcnt(7)\n\ts_barrier" ::: "memory");
        } else {
            asm volatile("s_waitcnt vmcnt(0)\n\ts_barrier" ::: "memory");
        }
        compute_ci(acc, rows[cur], halo[cur], wt, ci, y0, t, xlo, xhi);
        if (ci < 3)
            asm volatile("s_barrier" ::: "memory");  // readers done before
                                                     // next stage overwrites
    }

    const int x0g = X0 + 4 * t;
    #pragma unroll
    for (int o = 0; o < 4; ++o) {
        const long long obase = (long long)(y0 + o) * IW + x0g;
        #pragma unroll
        for (int co = 0; co < 4; ++co) {
            v4f ov;
            ov.x = acc[o][co][0]; ov.y = acc[o][co][1];
            ov.z = acc[o][co][2]; ov.w = acc[o][co][3];
            __builtin_nontemporal_store(ov,
                reinterpret_cast<v4f*>(out + co * HWsz + obase));
        }
    }
}

extern "C" void kernel_launch(void* const* d_in, const int* in_sizes, int n_in,
                              void* d_out, int out_size, void* d_ws, size_t ws_size,
                              hipStream_t stream) {
    const float* xin = (const float*)d_in[0];
    const float* wt  = (const float*)d_in[1];
    float* out       = (float*)d_out;

    dim3 grid(4096), block(256);
    hipLaunchKernelGGL(conv3x3_kernel, grid, block, 0, stream, xin, wt, out);
}